// Round 1
// baseline (343.852 us; speedup 1.0000x reference)
//
#include <hip/hip_runtime.h>
#include <hip/hip_bf16.h>

#define B_ 4
#define C_ 256
#define D_ 128
#define N_ 4096

typedef float f32x4 __attribute__((ext_vector_type(4)));
typedef short bf16x8 __attribute__((ext_vector_type(8)));
typedef unsigned short u16;

__device__ __forceinline__ u16 f2bf(float f) {
  unsigned u = __float_as_uint(f);
  u += 0x7fffu + ((u >> 16) & 1u);
  return (u16)(u >> 16);
}
__device__ __forceinline__ unsigned pack2(float a, float b) {
  return (unsigned)f2bf(a) | ((unsigned)f2bf(b) << 16);
}

// ---------------- projection: Q/K -> [N][D] bf16, V -> [D][N] bf16 ----------
__global__ __launch_bounds__(256) void proj_kernel(
    const float* __restrict__ x,
    const float* __restrict__ Wq, const float* __restrict__ Wk,
    const float* __restrict__ Wv,
    u16* __restrict__ Qo, u16* __restrict__ Ko, u16* __restrict__ Vt) {
  __shared__ float xs[64][68];    // [c][n] tile, pad 68 (16B-aligned rows)
  __shared__ float ws[128][68];   // [d][c] tile

  const int nt = blockIdx.x;      // n-tile (64)
  const int bm = blockIdx.y;      // b*3+m
  const int b = bm / 3, m = bm % 3;
  const float* __restrict__ W = (m == 0) ? Wq : (m == 1) ? Wk : Wv;
  const int n0 = nt * 64;
  const int t = threadIdx.x;
  const int nl = t & 31;          // n lane: handles n0+nl, n0+nl+32
  const int dg = t >> 5;          // d group of 16

  float acc[2][16];
#pragma unroll
  for (int a = 0; a < 2; ++a)
#pragma unroll
    for (int dd = 0; dd < 16; ++dd) acc[a][dd] = 0.f;

  for (int c0 = 0; c0 < C_; c0 += 64) {
    __syncthreads();
    {
      const int cr = t >> 2, nc0 = (t & 3) * 16;
      const float* src = x + ((size_t)b * C_ + c0 + cr) * N_ + n0 + nc0;
#pragma unroll
      for (int i = 0; i < 4; ++i)
        *(float4*)&xs[cr][nc0 + 4 * i] = *(const float4*)(src + 4 * i);
    }
    {
      const int dr = t >> 1, cc0 = (t & 1) * 32;
      const float* srcw = W + (size_t)dr * C_ + c0 + cc0;
#pragma unroll
      for (int i = 0; i < 8; ++i)
        *(float4*)&ws[dr][cc0 + 4 * i] = *(const float4*)(srcw + 4 * i);
    }
    __syncthreads();

    for (int cc = 0; cc < 64; cc += 4) {
#pragma unroll
      for (int h = 0; h < 2; ++h) {
        float4 wv[8];
#pragma unroll
        for (int dd = 0; dd < 8; ++dd)
          wv[dd] = *(const float4*)&ws[dg * 16 + h * 8 + dd][cc];
#pragma unroll
        for (int j = 0; j < 4; ++j) {
          const float x0 = xs[cc + j][nl];
          const float x1 = xs[cc + j][nl + 32];
#pragma unroll
          for (int dd = 0; dd < 8; ++dd) {
            const float wj = j == 0 ? wv[dd].x
                           : j == 1 ? wv[dd].y
                           : j == 2 ? wv[dd].z : wv[dd].w;
            acc[0][h * 8 + dd] = fmaf(x0, wj, acc[0][h * 8 + dd]);
            acc[1][h * 8 + dd] = fmaf(x1, wj, acc[1][h * 8 + dd]);
          }
        }
      }
    }
  }

  if (m < 2) {
    u16* __restrict__ O = (m == 0 ? Qo : Ko) + (size_t)b * N_ * D_;
#pragma unroll
    for (int a = 0; a < 2; ++a) {
      const int n = n0 + nl + 32 * a;
      uint4 p0, p1;
      p0.x = pack2(acc[a][0], acc[a][1]);
      p0.y = pack2(acc[a][2], acc[a][3]);
      p0.z = pack2(acc[a][4], acc[a][5]);
      p0.w = pack2(acc[a][6], acc[a][7]);
      p1.x = pack2(acc[a][8], acc[a][9]);
      p1.y = pack2(acc[a][10], acc[a][11]);
      p1.z = pack2(acc[a][12], acc[a][13]);
      p1.w = pack2(acc[a][14], acc[a][15]);
      *(uint4*)&O[(size_t)n * D_ + dg * 16] = p0;
      *(uint4*)&O[(size_t)n * D_ + dg * 16 + 8] = p1;
    }
  } else {
    u16* __restrict__ O = Vt + (size_t)b * D_ * N_;
#pragma unroll
    for (int dd = 0; dd < 16; ++dd)
#pragma unroll
      for (int a = 0; a < 2; ++a)
        O[(size_t)(dg * 16 + dd) * N_ + n0 + nl + 32 * a] = f2bf(acc[a][dd]);
  }
}

// ---------------- flash attention: out[b][d][n] ------------------------------
__global__ __launch_bounds__(256) void attn_kernel(
    const u16* __restrict__ Q, const u16* __restrict__ K,
    const u16* __restrict__ Vt, float* __restrict__ out) {
  constexpr int LKS = 136;  // lds_k row stride (bf16), pad +8
  constexpr int LVS = 72;   // lds_vt row stride
  constexpr int LPS = 72;   // lds_p row stride
  __shared__ __align__(16) u16 lds_k[64 * LKS];    // [kpos][d]
  __shared__ __align__(16) u16 lds_vt[128 * LVS];  // [d][kpos]
  __shared__ __align__(16) u16 lds_p[4][16 * LPS]; // per-wave [qlocal][kpos]

  const int b = blockIdx.y;
  const int q0 = blockIdx.x * 64;
  const int t = threadIdx.x;
  const int w = t >> 6, lane = t & 63;
  const int g = lane >> 4, c = lane & 15;

  const u16* __restrict__ Qb = Q + (size_t)b * N_ * D_;
  const u16* __restrict__ Kb = K + (size_t)b * N_ * D_;
  const u16* __restrict__ Vb = Vt + (size_t)b * D_ * N_;

  // A-frag of Q: lane holds Q[q0+w*16+c][kc*32 + g*8 + j]
  bf16x8 qf[4];
  {
    const int qrow = q0 + w * 16 + c;
#pragma unroll
    for (int kc = 0; kc < 4; ++kc)
      qf[kc] = *(const bf16x8*)&Qb[(size_t)qrow * D_ + kc * 32 + g * 8];
  }

  f32x4 acc[8];  // O^T frags: row d = dt*16+g*4+i, col qlocal = c
#pragma unroll
  for (int dt = 0; dt < 8; ++dt) acc[dt] = (f32x4){0.f, 0.f, 0.f, 0.f};
  float mrow[4] = {-3.0e38f, -3.0e38f, -3.0e38f, -3.0e38f};
  float lrow[4] = {0.f, 0.f, 0.f, 0.f};
  const float kE = 1.44269504f;

  for (int kt = 0; kt < N_ / 64; ++kt) {
    __syncthreads();
    // stage K tile [64][128] -> lds_k (row-major, padded)
#pragma unroll
    for (int i = 0; i < 4; ++i) {
      const int qd = i * 256 + t;
      const int r = qd >> 4, dc = (qd & 15) * 8;
      *(bf16x8*)&lds_k[r * LKS + dc] =
          *(const bf16x8*)&Kb[((size_t)(kt * 64 + r)) * D_ + dc];
    }
    // stage V^T tile [128][64] -> lds_vt (straight copy, V is [D][N])
#pragma unroll
    for (int i = 0; i < 4; ++i) {
      const int qd = i * 256 + t;
      const int d = qd >> 3, rc = (qd & 7) * 8;
      *(bf16x8*)&lds_vt[d * LVS + rc] =
          *(const bf16x8*)&Vb[(size_t)d * N_ + kt * 64 + rc];
    }
    __syncthreads();

    // S strip 16x64 = Q (A) * K^T (B)
    f32x4 s[4];
#pragma unroll
    for (int ct = 0; ct < 4; ++ct) s[ct] = (f32x4){0.f, 0.f, 0.f, 0.f};
#pragma unroll
    for (int kc = 0; kc < 4; ++kc) {
#pragma unroll
      for (int ct = 0; ct < 4; ++ct) {
        const bf16x8 kf =
            *(const bf16x8*)&lds_k[(ct * 16 + c) * LKS + kc * 32 + g * 8];
        s[ct] = __builtin_amdgcn_mfma_f32_16x16x32_bf16(qf[kc], kf, s[ct], 0, 0, 0);
      }
    }

    // online softmax; row r = g*4+i lives in 16-lane group g, reg i
    float scl[4];
#pragma unroll
    for (int i = 0; i < 4; ++i) {
      float m2 = fmaxf(fmaxf(s[0][i], s[1][i]), fmaxf(s[2][i], s[3][i]));
#pragma unroll
      for (int off = 1; off < 16; off <<= 1) m2 = fmaxf(m2, __shfl_xor(m2, off));
      const float mnew = fmaxf(mrow[i], m2);
      scl[i] = exp2f((mrow[i] - mnew) * kE);
      float rs = 0.f;
#pragma unroll
      for (int ct = 0; ct < 4; ++ct) {
        const float p = exp2f((s[ct][i] - mnew) * kE);
        s[ct][i] = p;
        rs += p;
      }
#pragma unroll
      for (int off = 1; off < 16; off <<= 1) rs += __shfl_xor(rs, off);
      lrow[i] = lrow[i] * scl[i] + rs;
      mrow[i] = mnew;
    }

    // rescale O^T acc: this lane's column is q-row c -> fetch its scale
    {
      const int src = (c >> 2) << 4;
      const float a0 = __shfl(scl[0], src), a1 = __shfl(scl[1], src);
      const float a2 = __shfl(scl[2], src), a3 = __shfl(scl[3], src);
      const int is = c & 3;
      const float sc = is == 0 ? a0 : is == 1 ? a1 : is == 2 ? a2 : a3;
#pragma unroll
      for (int dt = 0; dt < 8; ++dt) {
        acc[dt][0] *= sc; acc[dt][1] *= sc;
        acc[dt][2] *= sc; acc[dt][3] *= sc;
      }
    }

    // P -> per-wave LDS (bf16), layout [qlocal][kpos]
    u16* __restrict__ pw = lds_p[w];
#pragma unroll
    for (int ct = 0; ct < 4; ++ct)
#pragma unroll
      for (int i = 0; i < 4; ++i)
        pw[(g * 4 + i) * LPS + ct * 16 + c] = f2bf(s[ct][i]);

    // O^T += V^T (A) * P^T (B)
#pragma unroll
    for (int kc = 0; kc < 2; ++kc) {
      const bf16x8 pf = *(const bf16x8*)&pw[c * LPS + kc * 32 + g * 8];
#pragma unroll
      for (int dt = 0; dt < 8; ++dt) {
        const bf16x8 vf =
            *(const bf16x8*)&lds_vt[(dt * 16 + c) * LVS + kc * 32 + g * 8];
        acc[dt] = __builtin_amdgcn_mfma_f32_16x16x32_bf16(vf, pf, acc[dt], 0, 0, 0);
      }
    }
  }

  // epilogue: divide by row-sum (per column q-row = c), coalesced store
  {
    const int src = (c >> 2) << 4;
    const float a0 = __shfl(lrow[0], src), a1 = __shfl(lrow[1], src);
    const float a2 = __shfl(lrow[2], src), a3 = __shfl(lrow[3], src);
    const int is = c & 3;
    const float lsum = is == 0 ? a0 : is == 1 ? a1 : is == 2 ? a2 : a3;
    const float linv = 1.0f / lsum;
    const int n = q0 + w * 16 + c;
    float* __restrict__ ob = out + (size_t)b * D_ * N_;
#pragma unroll
    for (int dt = 0; dt < 8; ++dt)
#pragma unroll
      for (int i = 0; i < 4; ++i)
        ob[(size_t)(dt * 16 + g * 4 + i) * N_ + n] = acc[dt][i] * linv;
  }
}

extern "C" void kernel_launch(void* const* d_in, const int* in_sizes, int n_in,
                              void* d_out, int out_size, void* d_ws, size_t ws_size,
                              hipStream_t stream) {
  const float* x  = (const float*)d_in[0];
  const float* Wq = (const float*)d_in[1];
  const float* Wk = (const float*)d_in[2];
  const float* Wv = (const float*)d_in[3];
  float* out = (float*)d_out;

  u16* q_ws = (u16*)d_ws;                       // [B][N][D] bf16
  u16* k_ws = q_ws + (size_t)B_ * N_ * D_;      // [B][N][D] bf16
  u16* v_ws = k_ws + (size_t)B_ * N_ * D_;      // [B][D][N] bf16

  proj_kernel<<<dim3(64, 12), 256, 0, stream>>>(x, Wq, Wk, Wv, q_ws, k_ws, v_ws);
  attn_kernel<<<dim3(64, 4), 256, 0, stream>>>(q_ws, k_ws, v_ws, out);
}

// Round 3
// 162.207 us; speedup vs baseline: 2.1198x; 2.1198x over previous
//
#include <hip/hip_runtime.h>
#include <hip/hip_bf16.h>

#define B_ 4
#define C_ 256
#define D_ 128
#define N_ 4096

typedef float f32x4 __attribute__((ext_vector_type(4)));
typedef short bf16x8 __attribute__((ext_vector_type(8)));
typedef short s16x4 __attribute__((ext_vector_type(4)));
typedef unsigned short u16;
typedef unsigned int u32;

__device__ __forceinline__ u16 f2bf(float f) {
  unsigned u = __float_as_uint(f);
  u += 0x7fffu + ((u >> 16) & 1u);
  return (u16)(u >> 16);
}
__device__ __forceinline__ u32 pack2(float a, float b) {
  return (u32)f2bf(a) | ((u32)f2bf(b) << 16);
}

// ---------------- projection: Q/K -> [N][D] bf16, V -> [D][N] bf16 ----------
__global__ __launch_bounds__(256) void proj_kernel(
    const float* __restrict__ x,
    const float* __restrict__ Wq, const float* __restrict__ Wk,
    const float* __restrict__ Wv,
    u16* __restrict__ Qo, u16* __restrict__ Ko, u16* __restrict__ Vt) {
  __shared__ float xs[64][68];
  __shared__ float ws[128][68];

  const int nt = blockIdx.x;
  const int bm = blockIdx.y;
  const int b = bm / 3, m = bm % 3;
  const float* __restrict__ W = (m == 0) ? Wq : (m == 1) ? Wk : Wv;
  const int n0 = nt * 64;
  const int t = threadIdx.x;
  const int nl = t & 31;
  const int dg = t >> 5;

  float acc[2][16];
#pragma unroll
  for (int a = 0; a < 2; ++a)
#pragma unroll
    for (int dd = 0; dd < 16; ++dd) acc[a][dd] = 0.f;

  for (int c0 = 0; c0 < C_; c0 += 64) {
    __syncthreads();
    {
      const int cr = t >> 2, nc0 = (t & 3) * 16;
      const float* src = x + ((size_t)b * C_ + c0 + cr) * N_ + n0 + nc0;
#pragma unroll
      for (int i = 0; i < 4; ++i)
        *(float4*)&xs[cr][nc0 + 4 * i] = *(const float4*)(src + 4 * i);
    }
    {
      const int dr = t >> 1, cc0 = (t & 1) * 32;
      const float* srcw = W + (size_t)dr * C_ + c0 + cc0;
#pragma unroll
      for (int i = 0; i < 8; ++i)
        *(float4*)&ws[dr][cc0 + 4 * i] = *(const float4*)(srcw + 4 * i);
    }
    __syncthreads();

    for (int cc = 0; cc < 64; cc += 4) {
#pragma unroll
      for (int h = 0; h < 2; ++h) {
        float4 wv[8];
#pragma unroll
        for (int dd = 0; dd < 8; ++dd)
          wv[dd] = *(const float4*)&ws[dg * 16 + h * 8 + dd][cc];
#pragma unroll
        for (int j = 0; j < 4; ++j) {
          const float x0 = xs[cc + j][nl];
          const float x1 = xs[cc + j][nl + 32];
#pragma unroll
          for (int dd = 0; dd < 8; ++dd) {
            const float wj = j == 0 ? wv[dd].x
                           : j == 1 ? wv[dd].y
                           : j == 2 ? wv[dd].z : wv[dd].w;
            acc[0][h * 8 + dd] = fmaf(x0, wj, acc[0][h * 8 + dd]);
            acc[1][h * 8 + dd] = fmaf(x1, wj, acc[1][h * 8 + dd]);
          }
        }
      }
    }
  }

  if (m < 2) {
    u16* __restrict__ O = (m == 0 ? Qo : Ko) + (size_t)b * N_ * D_;
#pragma unroll
    for (int a = 0; a < 2; ++a) {
      const int n = n0 + nl + 32 * a;
      uint4 p0, p1;
      p0.x = pack2(acc[a][0], acc[a][1]);
      p0.y = pack2(acc[a][2], acc[a][3]);
      p0.z = pack2(acc[a][4], acc[a][5]);
      p0.w = pack2(acc[a][6], acc[a][7]);
      p1.x = pack2(acc[a][8], acc[a][9]);
      p1.y = pack2(acc[a][10], acc[a][11]);
      p1.z = pack2(acc[a][12], acc[a][13]);
      p1.w = pack2(acc[a][14], acc[a][15]);
      *(uint4*)&O[(size_t)n * D_ + dg * 16] = p0;
      *(uint4*)&O[(size_t)n * D_ + dg * 16 + 8] = p1;
    }
  } else {
    u16* __restrict__ O = Vt + (size_t)b * D_ * N_;
#pragma unroll
    for (int dd = 0; dd < 16; ++dd)
#pragma unroll
      for (int a = 0; a < 2; ++a)
        O[(size_t)(dg * 16 + dd) * N_ + n0 + nl + 32 * a] = f2bf(acc[a][dd]);
  }
}

// swizzled LDS index helpers (u16 units); XOR spreads banks, keeps 16B blocks
__device__ __forceinline__ int kIdx(int row, int col) {
  return row * 128 + (col ^ ((row & 7) << 3));
}
__device__ __forceinline__ int vIdx(int d, int col) {
  return d * 64 + (col ^ ((d & 7) << 3));
}
__device__ __forceinline__ int pIdx(int q, int col) {
  return q * 64 + (col ^ ((q & 7) << 3));
}

// ---------------- flash attention (split-K), writes partial O^T + m + l -----
__global__ __launch_bounds__(256, 4) void attn_kernel(
    const u16* __restrict__ Q, const u16* __restrict__ K,
    const u16* __restrict__ Vt, float* __restrict__ outp,
    float* __restrict__ mb, float* __restrict__ lb, int chunk) {
  __shared__ __align__(16) u16 lds_k[64 * 128];    // [kpos][d], swizzled
  __shared__ __align__(16) u16 lds_vt[128 * 64];   // [d][kpos], swizzled
  __shared__ __align__(16) u16 lds_p[4][16 * 64];  // per-wave [q][kpos], swz

  const int b = blockIdx.y;
  const int q0 = blockIdx.x * 64;
  const int sid = blockIdx.z;
  const int k0 = sid * chunk;
  const int NT = chunk >> 6;
  const int t = threadIdx.x;
  const int w = t >> 6, lane = t & 63;
  const int g = lane >> 4, c = lane & 15;

  const u16* __restrict__ Qb = Q + (size_t)b * N_ * D_;
  const u16* __restrict__ Kb = K + (size_t)b * N_ * D_;
  const u16* __restrict__ Vb = Vt + (size_t)b * D_ * N_;

  // Q fragment: lane holds Q[q0+w*16+c][kc*32 + g*8 + j]
  bf16x8 qf[4];
  {
    const int qrow = q0 + w * 16 + c;
#pragma unroll
    for (int kc = 0; kc < 4; ++kc)
      qf[kc] = *(const bf16x8*)&Qb[(size_t)qrow * D_ + kc * 32 + g * 8];
  }

  f32x4 acc[8];  // O^T frags: row d = dt*16+g*4+i, col q-local = c
#pragma unroll
  for (int dt = 0; dt < 8; ++dt) acc[dt] = (f32x4){0.f, 0.f, 0.f, 0.f};
  float mrow = -3.0e38f, lrow = 0.f;
  const float kE = 1.44269504f;

  bf16x8 krg[4], vrg[4];
  auto load_tile = [&](int kbase) {
#pragma unroll
    for (int i = 0; i < 4; ++i) {
      const int idx = i * 256 + t;
      krg[i] = *(const bf16x8*)&Kb[(size_t)(kbase + (idx >> 4)) * D_ + (idx & 15) * 8];
      vrg[i] = *(const bf16x8*)&Vb[(size_t)(idx >> 3) * N_ + kbase + (idx & 7) * 8];
    }
  };
  load_tile(k0);

  u16* __restrict__ pw = lds_p[w];

  for (int kt = 0; kt < NT; ++kt) {
    __syncthreads();
    // write staged tile to LDS (swizzled)
#pragma unroll
    for (int i = 0; i < 4; ++i) {
      const int idx = i * 256 + t;
      *(bf16x8*)&lds_k[kIdx(idx >> 4, (idx & 15) * 8)] = krg[i];
      *(bf16x8*)&lds_vt[vIdx(idx >> 3, (idx & 7) * 8)] = vrg[i];
    }
    // prefetch next tile (latency hides under compute below)
    if (kt + 1 < NT) load_tile(k0 + (kt + 1) * 64);
    __syncthreads();

    // S^T strip: mfma(A=K, B=Q) -> lane holds S[q=c][k=ct*16+g*4+i]
    f32x4 s[4];
#pragma unroll
    for (int ct = 0; ct < 4; ++ct) s[ct] = (f32x4){0.f, 0.f, 0.f, 0.f};
#pragma unroll
    for (int kc = 0; kc < 4; ++kc) {
#pragma unroll
      for (int ct = 0; ct < 4; ++ct) {
        const bf16x8 kf =
            *(const bf16x8*)&lds_k[kIdx(ct * 16 + c, kc * 32 + g * 8)];
        s[ct] = __builtin_amdgcn_mfma_f32_16x16x32_bf16(kf, qf[kc], s[ct], 0, 0, 0);
      }
    }

    // lane-local online softmax for q-row c (replicated across the 4 g-groups)
    float pm;
    {
      const float m0 = fmaxf(fmaxf(s[0][0], s[0][1]), fmaxf(s[0][2], s[0][3]));
      const float m1 = fmaxf(fmaxf(s[1][0], s[1][1]), fmaxf(s[1][2], s[1][3]));
      const float m2 = fmaxf(fmaxf(s[2][0], s[2][1]), fmaxf(s[2][2], s[2][3]));
      const float m3 = fmaxf(fmaxf(s[3][0], s[3][1]), fmaxf(s[3][2], s[3][3]));
      pm = fmaxf(fmaxf(m0, m1), fmaxf(m2, m3));
    }
    pm = fmaxf(pm, __shfl_xor(pm, 16));
    pm = fmaxf(pm, __shfl_xor(pm, 32));
    const float mnew = fmaxf(mrow, pm);
    const float scl = exp2f((mrow - mnew) * kE);
    float rs = 0.f;
#pragma unroll
    for (int ct = 0; ct < 4; ++ct)
#pragma unroll
      for (int i = 0; i < 4; ++i) {
        const float p = exp2f((s[ct][i] - mnew) * kE);
        s[ct][i] = p;
        rs += p;
      }
    rs += __shfl_xor(rs, 16);
    rs += __shfl_xor(rs, 32);
    lrow = lrow * scl + rs;
    mrow = mnew;
#pragma unroll
    for (int dt = 0; dt < 8; ++dt) {
      acc[dt][0] *= scl; acc[dt][1] *= scl;
      acc[dt][2] *= scl; acc[dt][3] *= scl;
    }

    // P^T -> per-wave LDS as bf16 (short-element vector: same TBAA node as
    // the bf16x8 reads below — u32 stores here get reordered past the reads)
#pragma unroll
    for (int ct = 0; ct < 4; ++ct) {
      const int pi = pIdx(c, ct * 16 + g * 4);
      s16x4 pv;
      pv[0] = (short)f2bf(s[ct][0]);
      pv[1] = (short)f2bf(s[ct][1]);
      pv[2] = (short)f2bf(s[ct][2]);
      pv[3] = (short)f2bf(s[ct][3]);
      *(s16x4*)&pw[pi] = pv;
    }
    // compiler fence: keep PV's LDS reads after the P stores (same-wave DS
    // ops execute in order on HW; only compiler reordering must be blocked)
    asm volatile("" ::: "memory");

    // O^T += V^T (A) * P^T (B)
#pragma unroll
    for (int kc = 0; kc < 2; ++kc) {
      const bf16x8 pf = *(const bf16x8*)&pw[pIdx(c, kc * 32 + g * 8)];
#pragma unroll
      for (int dt = 0; dt < 8; ++dt) {
        const bf16x8 vf =
            *(const bf16x8*)&lds_vt[vIdx(dt * 16 + c, kc * 32 + g * 8)];
        acc[dt] = __builtin_amdgcn_mfma_f32_16x16x32_bf16(vf, pf, acc[dt], 0, 0, 0);
      }
    }
  }

  const int n = q0 + w * 16 + c;
  if (mb) {
    // partial path: unnormalized O^T + stats
    float* __restrict__ ob = outp + ((size_t)(sid * B_ + b) * D_) * N_;
#pragma unroll
    for (int dt = 0; dt < 8; ++dt)
#pragma unroll
      for (int i = 0; i < 4; ++i)
        ob[(size_t)(dt * 16 + g * 4 + i) * N_ + n] = acc[dt][i];
    if (g == 0) {
      mb[(size_t)(sid * B_ + b) * N_ + n] = mrow;
      lb[(size_t)(sid * B_ + b) * N_ + n] = lrow;
    }
  } else {
    const float linv = 1.0f / lrow;
    float* __restrict__ ob = outp + (size_t)b * D_ * N_;
#pragma unroll
    for (int dt = 0; dt < 8; ++dt)
#pragma unroll
      for (int i = 0; i < 4; ++i)
        ob[(size_t)(dt * 16 + g * 4 + i) * N_ + n] = acc[dt][i] * linv;
  }
}

// ---------------- combine split-K partials -> out ---------------------------
__global__ __launch_bounds__(256) void combine_kernel(
    const float* __restrict__ op, const float* __restrict__ mbu,
    const float* __restrict__ lbu, float* __restrict__ out, int S) {
  const int idx = blockIdx.x * 256 + threadIdx.x;  // over B*D*(N/4)
  const int n0 = (idx & (N_ / 4 - 1)) * 4;
  const int bd = idx >> 10;
  const int b = bd >> 7, d = bd & (D_ - 1);
  const float kE = 1.44269504f;

  float4 msv[4], lsv[4];
  float M0 = -3e38f, M1 = -3e38f, M2 = -3e38f, M3 = -3e38f;
#pragma unroll
  for (int s = 0; s < 4; ++s)
    if (s < S) {
      msv[s] = *(const float4*)&mbu[(size_t)(s * B_ + b) * N_ + n0];
      lsv[s] = *(const float4*)&lbu[(size_t)(s * B_ + b) * N_ + n0];
      M0 = fmaxf(M0, msv[s].x); M1 = fmaxf(M1, msv[s].y);
      M2 = fmaxf(M2, msv[s].z); M3 = fmaxf(M3, msv[s].w);
    }
  float w0[4], w1[4], w2[4], w3[4];
  float d0 = 0.f, d1 = 0.f, d2 = 0.f, d3 = 0.f;
#pragma unroll
  for (int s = 0; s < 4; ++s)
    if (s < S) {
      w0[s] = exp2f((msv[s].x - M0) * kE); d0 += lsv[s].x * w0[s];
      w1[s] = exp2f((msv[s].y - M1) * kE); d1 += lsv[s].y * w1[s];
      w2[s] = exp2f((msv[s].z - M2) * kE); d2 += lsv[s].z * w2[s];
      w3[s] = exp2f((msv[s].w - M3) * kE); d3 += lsv[s].w * w3[s];
    }
  float a0 = 0.f, a1 = 0.f, a2 = 0.f, a3 = 0.f;
#pragma unroll
  for (int s = 0; s < 4; ++s)
    if (s < S) {
      const float4 o =
          *(const float4*)&op[((size_t)(s * B_ + b) * D_ + d) * N_ + n0];
      a0 += w0[s] * o.x; a1 += w1[s] * o.y;
      a2 += w2[s] * o.z; a3 += w3[s] * o.w;
    }
  float4 r = {a0 / d0, a1 / d1, a2 / d2, a3 / d3};
  *(float4*)&out[((size_t)b * D_ + d) * N_ + n0] = r;
}

extern "C" void kernel_launch(void* const* d_in, const int* in_sizes, int n_in,
                              void* d_out, int out_size, void* d_ws, size_t ws_size,
                              hipStream_t stream) {
  const float* x  = (const float*)d_in[0];
  const float* Wq = (const float*)d_in[1];
  const float* Wk = (const float*)d_in[2];
  const float* Wv = (const float*)d_in[3];
  float* out = (float*)d_out;

  u16* q_ws = (u16*)d_ws;                   // [B][N][D] bf16
  u16* k_ws = q_ws + (size_t)B_ * N_ * D_;  // [B][N][D] bf16
  u16* v_ws = k_ws + (size_t)B_ * N_ * D_;  // [B][D][N] bf16

  proj_kernel<<<dim3(64, 12), 256, 0, stream>>>(x, Wq, Wk, Wv, q_ws, k_ws, v_ws);

  const size_t qkvB = (size_t)3 * B_ * N_ * D_ * 2;
  int S = 0;
  for (int cand = 4; cand >= 1; cand >>= 1) {
    const size_t need = qkvB + (size_t)cand * ((size_t)B_ * D_ * N_ * 4 +
                                               (size_t)2 * B_ * N_ * 4);
    if (ws_size >= need) { S = cand; break; }
  }
  if (S > 0) {
    float* op = (float*)((char*)d_ws + qkvB);
    float* mbuf = op + (size_t)S * B_ * D_ * N_;
    float* lbuf = mbuf + (size_t)S * B_ * N_;
    attn_kernel<<<dim3(64, B_, S), 256, 0, stream>>>(q_ws, k_ws, v_ws, op,
                                                     mbuf, lbuf, N_ / S);
    combine_kernel<<<(B_ * D_ * N_ / 4) / 256, 256, 0, stream>>>(op, mbuf,
                                                                 lbuf, out, S);
  } else {
    attn_kernel<<<dim3(64, B_, 1), 256, 0, stream>>>(q_ws, k_ws, v_ws, out,
                                                     nullptr, nullptr, N_);
  }
}

// Round 5
// 103.451 us; speedup vs baseline: 3.3238x; 1.5680x over previous
//
#include <hip/hip_runtime.h>
#include <hip/hip_bf16.h>

#define B_ 4
#define C_ 256
#define D_ 128
#define N_ 4096

typedef float f32x4 __attribute__((ext_vector_type(4)));
typedef short bf16x8 __attribute__((ext_vector_type(8)));
typedef short s16x4 __attribute__((ext_vector_type(4)));
typedef unsigned short u16;
typedef unsigned int u32;

__device__ __forceinline__ u16 f2bf(float f) {
  unsigned u = __float_as_uint(f);
  u += 0x7fffu + ((u >> 16) & 1u);
  return (u16)(u >> 16);
}
__device__ __forceinline__ float bf2f(u16 v) {
  return __uint_as_float(((u32)v) << 16);
}

// ---------------- W cast: f32 -> hi/lo bf16 pair [3][128][256] ---------------
__global__ __launch_bounds__(256) void castw_kernel(
    const float* __restrict__ Wq, const float* __restrict__ Wk,
    const float* __restrict__ Wv, u16* __restrict__ Whi,
    u16* __restrict__ Wlo) {
  const int i = blockIdx.x * 256 + threadIdx.x;  // 24576 threads x 4 elems
  const int m = i >> 13;
  const int j = (i & 8191) * 4;
  const float* src = (m == 0) ? Wq : (m == 1) ? Wk : Wv;
  const float4 v = *(const float4*)(src + j);
  const float vv[4] = {v.x, v.y, v.z, v.w};
  s16x4 h, l;
#pragma unroll
  for (int k = 0; k < 4; ++k) {
    const u16 hb = f2bf(vv[k]);
    h[k] = (short)hb;
    l[k] = (short)f2bf(vv[k] - bf2f(hb));
  }
  *(s16x4*)&Whi[m * 32768 + j] = h;
  *(s16x4*)&Wlo[m * 32768 + j] = l;
}

// ------- projection via 3-term hi/lo MFMA: Q/K -> [N][D], V -> [D][N] -------
__global__ __launch_bounds__(256, 2) void proj_kernel(
    const float* __restrict__ x, const u16* __restrict__ Whi,
    const u16* __restrict__ Wlo, u16* __restrict__ Qo, u16* __restrict__ Ko,
    u16* __restrict__ Vt) {
  __shared__ __align__(16) u16 xs_h[32 * 256];  // x^T hi [n][c], swizzled
  __shared__ __align__(16) u16 xs_l[32 * 256];  // x^T lo

  const int n0 = blockIdx.x * 32;
  const int b = blockIdx.y;
  const int t = threadIdx.x;
  const int w = t >> 6, lane = t & 63, g = lane >> 4, c = lane & 15;

  // stage x^T hi/lo: coalesced float4 reads (4 n at fixed c-row)
  {
    const float* xb = x + ((size_t)b * C_) * N_ + n0;
#pragma unroll
    for (int r = 0; r < 8; ++r) {
      const int id = r * 256 + t;
      const int cr = id >> 3, nq = (id & 7) * 4;
      const float4 v = *(const float4*)(xb + (size_t)cr * N_ + nq);
      const float vv[4] = {v.x, v.y, v.z, v.w};
#pragma unroll
      for (int k2 = 0; k2 < 4; ++k2) {
        const int idx2 = (nq + k2) * 256 + (cr ^ (((nq + k2) & 7) << 3));
        const u16 hb = f2bf(vv[k2]);
        xs_h[idx2] = hb;
        xs_l[idx2] = f2bf(vv[k2] - bf2f(hb));
      }
    }
  }
  __syncthreads();

  if (w < 2) {
    // Q (w=0) / K (w=1): C[n][d] = mfma(A=x^T, B=W^T) with hi/lo compensation
    const size_t wo = (size_t)w * 32768;
    u16* __restrict__ O = (w == 0 ? Qo : Ko) + (size_t)b * N_ * D_;
#pragma unroll 1
    for (int dt = 0; dt < 8; ++dt) {
      bf16x8 wfh[8], wfl[8];
#pragma unroll
      for (int kc = 0; kc < 8; ++kc) {
        const size_t off = wo + (size_t)(dt * 16 + c) * 256 + kc * 32 + g * 8;
        wfh[kc] = *(const bf16x8*)&Whi[off];
        wfl[kc] = *(const bf16x8*)&Wlo[off];
      }
#pragma unroll
      for (int nt = 0; nt < 2; ++nt) {
        f32x4 a = {0.f, 0.f, 0.f, 0.f};
#pragma unroll
        for (int kc = 0; kc < 8; ++kc) {
          const int xi = (nt * 16 + c) * 256 +
                         ((kc * 32 + g * 8) ^ ((c & 7) << 3));
          const bf16x8 xh = *(const bf16x8*)&xs_h[xi];
          const bf16x8 xl = *(const bf16x8*)&xs_l[xi];
          a = __builtin_amdgcn_mfma_f32_16x16x32_bf16(xh, wfh[kc], a, 0, 0, 0);
          a = __builtin_amdgcn_mfma_f32_16x16x32_bf16(xh, wfl[kc], a, 0, 0, 0);
          a = __builtin_amdgcn_mfma_f32_16x16x32_bf16(xl, wfh[kc], a, 0, 0, 0);
        }
#pragma unroll
        for (int i = 0; i < 4; ++i)
          O[(size_t)(n0 + nt * 16 + g * 4 + i) * D_ + dt * 16 + c] = f2bf(a[i]);
      }
    }
  } else {
    // V (w=2,3 halves): C[d][n] = mfma(A=W, B=x) with hi/lo compensation
    const size_t wo = (size_t)2 * 32768;
    const int d0 = (w - 2) * 64;
    u16* __restrict__ O = Vt + (size_t)b * D_ * N_;
#pragma unroll 1
    for (int dt = 0; dt < 4; ++dt) {
      bf16x8 wfh[8], wfl[8];
#pragma unroll
      for (int kc = 0; kc < 8; ++kc) {
        const size_t off =
            wo + (size_t)(d0 + dt * 16 + c) * 256 + kc * 32 + g * 8;
        wfh[kc] = *(const bf16x8*)&Whi[off];
        wfl[kc] = *(const bf16x8*)&Wlo[off];
      }
#pragma unroll
      for (int nt = 0; nt < 2; ++nt) {
        f32x4 a = {0.f, 0.f, 0.f, 0.f};
#pragma unroll
        for (int kc = 0; kc < 8; ++kc) {
          const int xi = (nt * 16 + c) * 256 +
                         ((kc * 32 + g * 8) ^ ((c & 7) << 3));
          const bf16x8 xh = *(const bf16x8*)&xs_h[xi];
          const bf16x8 xl = *(const bf16x8*)&xs_l[xi];
          a = __builtin_amdgcn_mfma_f32_16x16x32_bf16(wfh[kc], xh, a, 0, 0, 0);
          a = __builtin_amdgcn_mfma_f32_16x16x32_bf16(wfl[kc], xh, a, 0, 0, 0);
          a = __builtin_amdgcn_mfma_f32_16x16x32_bf16(wfh[kc], xl, a, 0, 0, 0);
        }
#pragma unroll
        for (int i = 0; i < 4; ++i)
          O[(size_t)(d0 + dt * 16 + g * 4 + i) * N_ + n0 + nt * 16 + c] =
              f2bf(a[i]);
      }
    }
  }
}

// swizzled LDS index helpers (u16 units)
__device__ __forceinline__ int kIdx(int row, int col) {
  return row * 128 + (col ^ ((row & 7) << 3));
}
__device__ __forceinline__ int vIdx(int d, int col) {
  return d * 64 + (col ^ ((d & 7) << 3));
}
__device__ __forceinline__ int pIdx(int q, int col) {
  return q * 64 + (col ^ ((q & 7) << 3));
}

// ---------------- flash attention (split-K), 32 q-rows per wave -------------
__global__ __launch_bounds__(256, 2) void attn_kernel(
    const u16* __restrict__ Q, const u16* __restrict__ K,
    const u16* __restrict__ Vt, float* __restrict__ outp,
    float* __restrict__ mb, float* __restrict__ lb, int chunk) {
  __shared__ __align__(16) u16 lds_k[64 * 128];    // [kpos][d], swizzled
  __shared__ __align__(16) u16 lds_vt[128 * 64];   // [d][kpos], swizzled
  __shared__ __align__(16) u16 lds_p[4][32 * 64];  // per-wave [q][kpos], swz

  const int b = blockIdx.y;
  const int sid = blockIdx.z;
  const int q0 = blockIdx.x * 128;
  const int k0 = sid * chunk;
  const int NT = chunk >> 6;
  const int t = threadIdx.x;
  const int w = t >> 6, lane = t & 63, g = lane >> 4, c = lane & 15;
  const int qw = q0 + w * 32;

  const u16* __restrict__ Qb = Q + (size_t)b * N_ * D_;
  const u16* __restrict__ Kb = K + (size_t)b * N_ * D_;
  const u16* __restrict__ Vb = Vt + (size_t)b * D_ * N_;

  bf16x8 qf[2][4];
#pragma unroll
  for (int qh = 0; qh < 2; ++qh)
#pragma unroll
    for (int kc = 0; kc < 4; ++kc)
      qf[qh][kc] =
          *(const bf16x8*)&Qb[(size_t)(qw + qh * 16 + c) * D_ + kc * 32 + g * 8];

  f32x4 acc[8][2];  // O^T frags: row d = dt*16+g*4+i, col q = qh*16 + c
#pragma unroll
  for (int dt = 0; dt < 8; ++dt)
#pragma unroll
    for (int qh = 0; qh < 2; ++qh) acc[dt][qh] = (f32x4){0.f, 0.f, 0.f, 0.f};
  float mrow[2] = {-3.0e38f, -3.0e38f};
  float lrow[2] = {0.f, 0.f};
  const float kE = 1.44269504f;

  bf16x8 krg[4], vrg[4];
  auto load_tile = [&](int kbase) {
#pragma unroll
    for (int i = 0; i < 4; ++i) {
      const int idx = i * 256 + t;
      krg[i] = *(const bf16x8*)&Kb[(size_t)(kbase + (idx >> 4)) * D_ + (idx & 15) * 8];
      vrg[i] = *(const bf16x8*)&Vb[(size_t)(idx >> 3) * N_ + kbase + (idx & 7) * 8];
    }
  };
  load_tile(k0);

  u16* __restrict__ pw = lds_p[w];

  for (int kt = 0; kt < NT; ++kt) {
    __syncthreads();
#pragma unroll
    for (int i = 0; i < 4; ++i) {
      const int idx = i * 256 + t;
      *(bf16x8*)&lds_k[kIdx(idx >> 4, (idx & 15) * 8)] = krg[i];
      *(bf16x8*)&lds_vt[vIdx(idx >> 3, (idx & 7) * 8)] = vrg[i];
    }
    if (kt + 1 < NT) load_tile(k0 + (kt + 1) * 64);  // async prefetch
    __syncthreads();

    // S^T: mfma(A=K, B=Q) -> lane holds S[q=qh*16+c][k=ct*16+g*4+i]
    f32x4 s[4][2];
#pragma unroll
    for (int ct = 0; ct < 4; ++ct)
#pragma unroll
      for (int qh = 0; qh < 2; ++qh) s[ct][qh] = (f32x4){0.f, 0.f, 0.f, 0.f};
#pragma unroll
    for (int kc = 0; kc < 4; ++kc) {
#pragma unroll
      for (int ct = 0; ct < 4; ++ct) {
        const bf16x8 kf =
            *(const bf16x8*)&lds_k[kIdx(ct * 16 + c, kc * 32 + g * 8)];
        s[ct][0] = __builtin_amdgcn_mfma_f32_16x16x32_bf16(kf, qf[0][kc], s[ct][0], 0, 0, 0);
        s[ct][1] = __builtin_amdgcn_mfma_f32_16x16x32_bf16(kf, qf[1][kc], s[ct][1], 0, 0, 0);
      }
    }

    // per-q-row online softmax (lane-local; replicated across g)
    float pm[2];
#pragma unroll
    for (int qh = 0; qh < 2; ++qh) {
      const float m0 = fmaxf(fmaxf(s[0][qh][0], s[0][qh][1]),
                             fmaxf(s[0][qh][2], s[0][qh][3]));
      const float m1 = fmaxf(fmaxf(s[1][qh][0], s[1][qh][1]),
                             fmaxf(s[1][qh][2], s[1][qh][3]));
      const float m2 = fmaxf(fmaxf(s[2][qh][0], s[2][qh][1]),
                             fmaxf(s[2][qh][2], s[2][qh][3]));
      const float m3 = fmaxf(fmaxf(s[3][qh][0], s[3][qh][1]),
                             fmaxf(s[3][qh][2], s[3][qh][3]));
      float p = fmaxf(fmaxf(m0, m1), fmaxf(m2, m3));
      p = fmaxf(p, __shfl_xor(p, 16));
      p = fmaxf(p, __shfl_xor(p, 32));
      pm[qh] = p;
    }
    // defer-max (T13): rescale only when a row grew past THR=8
    const bool need =
        __any((pm[0] > mrow[0] + 8.f) || (pm[1] > mrow[1] + 8.f));
    if (need) {
#pragma unroll
      for (int qh = 0; qh < 2; ++qh) {
        const float mnew = fmaxf(mrow[qh], pm[qh]);
        const float scl = exp2f((mrow[qh] - mnew) * kE);
        lrow[qh] *= scl;
        mrow[qh] = mnew;
#pragma unroll
        for (int dt = 0; dt < 8; ++dt) {
          acc[dt][qh][0] *= scl; acc[dt][qh][1] *= scl;
          acc[dt][qh][2] *= scl; acc[dt][qh][3] *= scl;
        }
      }
    }
#pragma unroll
    for (int qh = 0; qh < 2; ++qh) {
      float rs = 0.f;
#pragma unroll
      for (int ct = 0; ct < 4; ++ct)
#pragma unroll
        for (int i = 0; i < 4; ++i) {
          const float p = exp2f((s[ct][qh][i] - mrow[qh]) * kE);
          s[ct][qh][i] = p;
          rs += p;
        }
      rs += __shfl_xor(rs, 16);
      rs += __shfl_xor(rs, 32);
      lrow[qh] += rs;
    }

    // P^T -> per-wave LDS (bf16, short-typed stores: alias-compatible)
#pragma unroll
    for (int qh = 0; qh < 2; ++qh)
#pragma unroll
      for (int ct = 0; ct < 4; ++ct) {
        const int pi = pIdx(qh * 16 + c, ct * 16 + g * 4);
        s16x4 pv;
        pv[0] = (short)f2bf(s[ct][qh][0]);
        pv[1] = (short)f2bf(s[ct][qh][1]);
        pv[2] = (short)f2bf(s[ct][qh][2]);
        pv[3] = (short)f2bf(s[ct][qh][3]);
        *(s16x4*)&pw[pi] = pv;
      }
    asm volatile("" ::: "memory");  // keep PV reads after P stores

    // O^T += V^T (A) * P^T (B); V frags shared across both q-halves
#pragma unroll
    for (int kc = 0; kc < 2; ++kc) {
      const bf16x8 pf0 = *(const bf16x8*)&pw[pIdx(c, kc * 32 + g * 8)];
      const bf16x8 pf1 = *(const bf16x8*)&pw[pIdx(16 + c, kc * 32 + g * 8)];
#pragma unroll
      for (int dt = 0; dt < 8; ++dt) {
        const bf16x8 vf =
            *(const bf16x8*)&lds_vt[vIdx(dt * 16 + c, kc * 32 + g * 8)];
        acc[dt][0] = __builtin_amdgcn_mfma_f32_16x16x32_bf16(vf, pf0, acc[dt][0], 0, 0, 0);
        acc[dt][1] = __builtin_amdgcn_mfma_f32_16x16x32_bf16(vf, pf1, acc[dt][1], 0, 0, 0);
      }
    }
  }

#pragma unroll
  for (int qh = 0; qh < 2; ++qh) {
    const int n = qw + qh * 16 + c;
    if (mb) {
      // partial path: unnormalized O^T (f32) + stats
      float* __restrict__ ob = outp + ((size_t)(sid * B_ + b) * D_) * N_;
#pragma unroll
      for (int dt = 0; dt < 8; ++dt)
#pragma unroll
        for (int i = 0; i < 4; ++i)
          ob[(size_t)(dt * 16 + g * 4 + i) * N_ + n] = acc[dt][qh][i];
      if (g == 0) {
        mb[(size_t)(sid * B_ + b) * N_ + n] = mrow[qh];
        lb[(size_t)(sid * B_ + b) * N_ + n] = lrow[qh];
      }
    } else {
      const float linv = 1.0f / lrow[qh];
      float* __restrict__ ob = outp + (size_t)b * D_ * N_;
#pragma unroll
      for (int dt = 0; dt < 8; ++dt)
#pragma unroll
        for (int i = 0; i < 4; ++i)
          ob[(size_t)(dt * 16 + g * 4 + i) * N_ + n] = acc[dt][qh][i] * linv;
    }
  }
}

// ---------------- combine split-K partials (f32) -> out ---------------------
__global__ __launch_bounds__(256) void combine_kernel(
    const float* __restrict__ op, const float* __restrict__ mbu,
    const float* __restrict__ lbu, float* __restrict__ out, int S) {
  const int idx = blockIdx.x * 256 + threadIdx.x;  // over B*D*(N/4)
  const int n0 = (idx & (N_ / 4 - 1)) * 4;
  const int bd = idx >> 10;
  const int b = bd >> 7, d = bd & (D_ - 1);
  const float kE = 1.44269504f;

  float4 msv[4], lsv[4];
  float M0 = -3e38f, M1 = -3e38f, M2 = -3e38f, M3 = -3e38f;
#pragma unroll
  for (int s = 0; s < 4; ++s)
    if (s < S) {
      msv[s] = *(const float4*)&mbu[(size_t)(s * B_ + b) * N_ + n0];
      lsv[s] = *(const float4*)&lbu[(size_t)(s * B_ + b) * N_ + n0];
      M0 = fmaxf(M0, msv[s].x); M1 = fmaxf(M1, msv[s].y);
      M2 = fmaxf(M2, msv[s].z); M3 = fmaxf(M3, msv[s].w);
    }
  float w0[4], w1[4], w2[4], w3[4];
  float d0 = 0.f, d1 = 0.f, d2 = 0.f, d3 = 0.f;
#pragma unroll
  for (int s = 0; s < 4; ++s)
    if (s < S) {
      w0[s] = exp2f((msv[s].x - M0) * kE); d0 += lsv[s].x * w0[s];
      w1[s] = exp2f((msv[s].y - M1) * kE); d1 += lsv[s].y * w1[s];
      w2[s] = exp2f((msv[s].z - M2) * kE); d2 += lsv[s].z * w2[s];
      w3[s] = exp2f((msv[s].w - M3) * kE); d3 += lsv[s].w * w3[s];
    }
  float a0 = 0.f, a1 = 0.f, a2 = 0.f, a3 = 0.f;
#pragma unroll
  for (int s = 0; s < 4; ++s)
    if (s < S) {
      const float4 o =
          *(const float4*)&op[((size_t)(s * B_ + b) * D_ + d) * N_ + n0];
      a0 += w0[s] * o.x; a1 += w1[s] * o.y;
      a2 += w2[s] * o.z; a3 += w3[s] * o.w;
    }
  float4 r = {a0 / d0, a1 / d1, a2 / d2, a3 / d3};
  *(float4*)&out[((size_t)b * D_ + d) * N_ + n0] = r;
}

extern "C" void kernel_launch(void* const* d_in, const int* in_sizes, int n_in,
                              void* d_out, int out_size, void* d_ws, size_t ws_size,
                              hipStream_t stream) {
  const float* x  = (const float*)d_in[0];
  const float* Wq = (const float*)d_in[1];
  const float* Wk = (const float*)d_in[2];
  const float* Wv = (const float*)d_in[3];
  float* out = (float*)d_out;

  u16* whi  = (u16*)d_ws;                      // [3][128][256] bf16 hi
  u16* wlo  = whi + (size_t)3 * 128 * 256;     // [3][128][256] bf16 lo
  u16* q_ws = wlo + (size_t)3 * 128 * 256;     // [B][N][D] bf16
  u16* k_ws = q_ws + (size_t)B_ * N_ * D_;     // [B][N][D] bf16
  u16* v_ws = k_ws + (size_t)B_ * N_ * D_;     // [B][D][N] bf16

  castw_kernel<<<96, 256, 0, stream>>>(Wq, Wk, Wv, whi, wlo);
  proj_kernel<<<dim3(N_ / 32, B_), 256, 0, stream>>>(x, whi, wlo, q_ws, k_ws,
                                                     v_ws);

  const size_t baseB =
      ((size_t)6 * 128 * 256 + (size_t)3 * B_ * N_ * D_) * 2;
  int S = 0;
  for (int cand = 4; cand >= 1; cand >>= 1) {
    const size_t need = baseB + (size_t)cand * ((size_t)B_ * D_ * N_ * 4 +
                                                (size_t)2 * B_ * N_ * 4);
    if (ws_size >= need) { S = cand; break; }
  }
  if (S > 0) {
    float* op = (float*)((char*)d_ws + baseB);
    float* mbuf = op + (size_t)S * B_ * D_ * N_;
    float* lbuf = mbuf + (size_t)S * B_ * N_;
    attn_kernel<<<dim3(N_ / 128, B_, S), 256, 0, stream>>>(
        q_ws, k_ws, v_ws, op, mbuf, lbuf, N_ / S);
    combine_kernel<<<(B_ * D_ * N_ / 4) / 256, 256, 0, stream>>>(op, mbuf,
                                                                 lbuf, out, S);
  } else {
    attn_kernel<<<dim3(N_ / 128, B_, 1), 256, 0, stream>>>(
        q_ws, k_ws, v_ws, out, nullptr, nullptr, N_);
  }
}